// Round 2
// baseline (1122.213 us; speedup 1.0000x reference)
//
#include <hip/hip_runtime.h>
#include <stdint.h>
#include <stddef.h>

// Globally disable FP contraction: we are bit-exactly emulating the
// reference's per-op float32/float64 rounding; hipcc's default
// -ffp-contract=fast would fuse mul+add chains and change results.
#pragma clang fp contract(off)

// ===========================================================================
// SoftMD5 exact-forward emulation.
//
// Reference semantics (JAX, x64, CPU):
//   soft_add32(a,b) forward = fp32((hard + proxy) - proxy),
//     hard  = bits of floor(fmod(dot64(a) + dot64(b), 2^32))   [float64]
//     proxy = 0.5 * fp32(soft_xor(a,b))                        [float32]
// For hard=1 and fractional proxy the forward bit can be w := 1-2^-24
// ("dirty"). Dirty bits shift later float64 dots by -2^(k-24) => must be
// tracked exactly. All soft_add32 outputs lie in {0, 1, w} (proof: the
// rounding error of RN32(1+p) is in [-2^-24, 2^-24]).
//
// State representation: per 32-bit word, two u32 masks (hard, dirty),
// invariant dirty ⊆ hard.
//
// f64 dot-product order hypothesis (ROUND 1): STRICT SEQUENTIAL k=0..31
// (XLA:CPU elemental reduce). Alternates if this fails:
//   B) numpy pairwise (8 accumulators stride 8, tree combine)
//   C) 8-lane vector strided + halving shuffle tree (AVX-512 codegen)
// Order-specific pieces: sum_packed(), the accF chain, and the Wv chains.
// ===========================================================================

__device__ __forceinline__ uint32_t rotl32(uint32_t x, uint32_t n) {
    return (x << n) | (x >> (32u - n));
}

// Exact emulation of the sequential f64 sum of v_k * 2^k for a packed
// {0,1,w} vector. Partial sums through k=28 are multiples of 2^-24 below
// 2^29 => exactly representable (any grouping), so sequential partial sum
// S28 equals the closed form; only the k=29,30,31 adds round (emulated
// with one RN add each, in order).
__device__ __forceinline__ double sum_packed(uint32_t h, uint32_t d) {
#pragma clang fp contract(off)
    double s = (double)(h & 0x1FFFFFFFu) - 0x1p-24 * (double)(d & 0x1FFFFFFFu);
    s = s + ((double)((h >> 29) & 1u) * 0x1p29 - (double)((d >> 29) & 1u) * 0x1p5);
    s = s + ((double)((h >> 30) & 1u) * 0x1p30 - (double)((d >> 30) & 1u) * 0x1p6);
    s = s + ((double)((h >> 31) & 1u) * 0x1p31 - (double)((d >> 31) & 1u) * 0x1p7);
    return s;
}

// fmod(v, 2^32) for v in [0, 2^33 + small): exact conditional subtracts.
__device__ __forceinline__ double modred(double v) {
    if (v >= 0x1p33) v -= 0x1p33;
    if (v >= 0x1p32) v -= 0x1p32;
    return v;
}

// Unpack one packed bit to its f32 value: 0, 1, or w = 1 - 2^-24 (exact).
__device__ __forceinline__ float unpk(uint32_t h, uint32_t d, int k) {
#pragma clang fp contract(off)
    return (float)((h >> k) & 1u) - 0x1p-24f * (float)((d >> k) & 1u);
}

// Dirtiness of soft_add32's forward output bit given operand bit values x,y
// (meaningful when the hard output bit is 1): replicate the reference's
// float32 chain literally. proxy p = 0.5*((x+y) - (2x)*y);
// out = (1+p)-p; dirty <=> out != 1.
__device__ __forceinline__ uint32_t dflag(float x, float y, int k) {
#pragma clang fp contract(off)
    float u = x + y;
    float v = (2.0f * x) * y;
    float xr = u - v;
    float p = 0.5f * xr;
    float t = (1.0f + p) - p;
    return (t != 1.0f) ? (1u << k) : 0u;
}

// Loop-1 body: compute f0 bits (honest f32), sequential f64 sum of f0,
// and the proxy-dirtiness mask vs state word A. F0 computation passed as
// statements defining `f0` from fb, fc, fdd.
#define LOOP1(...)                                                            \
    {                                                                         \
        _Pragma("unroll")                                                     \
        for (int k = 0; k < 32; ++k) {                                        \
            float fb  = unpk(Bh, Bd, k);                                      \
            float fc  = unpk(Ch, Cd, k);                                      \
            float fdd = unpk(Dh, Dd, k);                                      \
            float f0;                                                         \
            __VA_ARGS__                                                       \
            accF = fma((double)f0, (double)(1u << k), accF);                  \
            float fa = unpk(Ah, Ad, k);                                       \
            df1 |= dflag(f0, fa, k);                                          \
        }                                                                     \
    }

__global__ __launch_bounds__(256) void softmd5_kernel(
    const float* __restrict__ msg, float* __restrict__ out, int B)
{
#pragma clang fp contract(off)
    static const uint32_t Ktab[64] = {
        0xd76aa478u, 0xe8c7b756u, 0x242070dbu, 0xc1bdceeeu,
        0xf57c0fafu, 0x4787c62au, 0xa8304613u, 0xfd469501u,
        0x698098d8u, 0x8b44f7afu, 0xffff5bb1u, 0x895cd7beu,
        0x6b901122u, 0xfd987193u, 0xa679438eu, 0x49b40821u,
        0xf61e2562u, 0xc040b340u, 0x265e5a51u, 0xe9b6c7aau,
        0xd62f105du, 0x02441453u, 0xd8a1e681u, 0xe7d3fbc8u,
        0x21e1cde6u, 0xc33707d6u, 0xf4d50d87u, 0x455a14edu,
        0xa9e3e905u, 0xfcefa3f8u, 0x676f02d9u, 0x8d2a4c8au,
        0xfffa3942u, 0x8771f681u, 0x6d9d6122u, 0xfde5380cu,
        0xa4beea44u, 0x4bdecfa9u, 0xf6bb4b60u, 0xbebfbc70u,
        0x289b7ec6u, 0xeaa127fau, 0xd4ef3085u, 0x04881d05u,
        0xd9d4d039u, 0xe6db99e5u, 0x1fa27cf8u, 0xc4ac5665u,
        0xf4292244u, 0x432aff97u, 0xab9423a7u, 0xfc93a039u,
        0x655b59c3u, 0x8f0ccc92u, 0xffeff47du, 0x85845dd1u,
        0x6fa87e4fu, 0xfe2ce6e0u, 0xa3014314u, 0x4e0811a1u,
        0xf7537e82u, 0xbd3af235u, 0x2ad7d2bbu, 0xeb86d391u
    };
    static const uint32_t Stab[64] = {
        7,12,17,22, 7,12,17,22, 7,12,17,22, 7,12,17,22,
        5, 9,14,20, 5, 9,14,20, 5, 9,14,20, 5, 9,14,20,
        4,11,16,23, 4,11,16,23, 4,11,16,23, 4,11,16,23,
        6,10,15,21, 6,10,15,21, 6,10,15,21, 6,10,15,21
    };
    static const uint32_t PW[16] = {
        128u,0,0,0, 0,0,0,0, 0,0,0,0, 0,0,512u,0
    };

    __shared__ double lds_wv[16][256];   // [word][tid]: bank-conflict-free

    const int tid = threadIdx.x;
    const int e = blockIdx.x * blockDim.x + tid;
    if (e >= B) return;

    const float* row = msg + (size_t)e * 512;

    // ---- per-word message values: sequential f64 sum k=0..31 (hyp. A) ----
    {
        const float4* r4 = reinterpret_cast<const float4*>(row);
        #pragma unroll
        for (int w = 0; w < 16; ++w) {
            double acc = 0.0;
            #pragma unroll
            for (int q = 0; q < 8; ++q) {
                float4 vv = r4[w * 8 + q];
                acc = fma((double)vv.x, (double)(1u << (4*q + 0)), acc);
                acc = fma((double)vv.y, (double)(1u << (4*q + 1)), acc);
                acc = fma((double)vv.z, (double)(1u << (4*q + 2)), acc);
                acc = fma((double)vv.w, (double)(1u << (4*q + 3)), acc);
            }
            lds_wv[w][tid] = acc;
        }
    }

    uint32_t Ah = 0x67452301u, Ad = 0u;
    uint32_t Bh = 0xefcdab89u, Bd = 0u;
    uint32_t Ch = 0x98badcfeu, Cd = 0u;
    uint32_t Dh = 0x10325476u, Dd = 0u;

    for (int blk = 0; blk < 2; ++blk) {
        const uint32_t sAh = Ah, sAd = Ad, sBh = Bh, sBd = Bd;
        const uint32_t sCh = Ch, sCd = Cd, sDh = Dh, sDd = Dd;

        for (int i = 0; i < 64; ++i) {
            const int type = i >> 4;
            const int g = (type == 0) ? i
                        : (type == 1) ? ((5 * i + 1) & 15)
                        : (type == 2) ? ((3 * i + 5) & 15)
                        :               ((7 * i) & 15);
            const uint32_t Kv = Ktab[i];

            // ---- add #1: f = soft_add32(f0, a) ----
            double accF = 0.0;
            uint32_t df1 = 0;
            if (type == 0) {
                // or(and(b,c), and(not b, d))
                LOOP1( float t1 = fb * fc; float nb = 1.0f - fb;
                       float t2 = nb * fdd;
                       float uu = t1 + t2; float vv = t1 * t2;
                       f0 = uu - vv; )
            } else if (type == 1) {
                // or(and(d,b), and(not d, c))
                LOOP1( float t1 = fdd * fb; float nd = 1.0f - fdd;
                       float t2 = nd * fc;
                       float uu = t1 + t2; float vv = t1 * t2;
                       f0 = uu - vv; )
            } else if (type == 2) {
                // xor(xor(b,c), d)
                LOOP1( float u1 = fb + fc; float v1 = (2.0f * fb) * fc;
                       float x1 = u1 - v1;
                       float u2 = x1 + fdd; float v2 = (2.0f * x1) * fdd;
                       f0 = u2 - v2; )
            } else {
                // xor(c, or(b, not d))
                LOOP1( float nd = 1.0f - fdd;
                       float u1 = fb + nd; float v1 = fb * nd;
                       float o = u1 - v1;
                       float u2 = fc + o; float v2 = (2.0f * fc) * o;
                       f0 = u2 - v2; )
            }
            double s1 = modred(accF + sum_packed(Ah, Ad));
            uint32_t h1 = (uint32_t)s1, d1 = h1 & df1;

            // ---- add #2: f = soft_add32(f, K[i]) (K hard) ----
            double s2 = modred(sum_packed(h1, d1) + (double)Kv);
            uint32_t h2 = (uint32_t)s2;
            uint32_t d2 = h2 & d1 & Kv;   // dirty only for (w,1) operand bits

            // ---- add #3: f = soft_add32(f, words[g]) ----
            uint32_t df3;
            double bv;
            if (blk == 0) {
                const float4* wb4 =
                    reinterpret_cast<const float4*>(row + (g << 5));
                uint32_t m = 0;
                #pragma unroll
                for (int q = 0; q < 8; ++q) {
                    float4 wv = wb4[q];
                    m |= dflag(unpk(h2, d2, 4*q + 0), wv.x, 4*q + 0);
                    m |= dflag(unpk(h2, d2, 4*q + 1), wv.y, 4*q + 1);
                    m |= dflag(unpk(h2, d2, 4*q + 2), wv.z, 4*q + 2);
                    m |= dflag(unpk(h2, d2, 4*q + 3), wv.w, 4*q + 3);
                }
                df3 = m;
                bv = lds_wv[g][tid];
            } else {
                const uint32_t pw = PW[g];
                df3 = d2 & pw;            // pad word bits are hard 0/1
                bv = (double)pw;
            }
            double s3 = modred(sum_packed(h2, d2) + bv);
            uint32_t h3 = (uint32_t)s3, d3 = h3 & df3;

            // ---- rotate + add #4: b = soft_add32(b, rotl(f)) ----
            const uint32_t sh = Stab[i];
            uint32_t rh = rotl32(h3, sh), rd = rotl32(d3, sh);
            double s4 = modred(sum_packed(Bh, Bd) + sum_packed(rh, rd));
            uint32_t h4 = (uint32_t)s4;
            uint32_t d4 = h4 & (Bh & rh) & (Bd | rd);  // {1,w}x{1,w} w/ dirt

            // ---- a,d,c = d,c,b; b = new ----
            Ah = Dh; Ad = Dd;
            Dh = Ch; Dd = Cd;
            Ch = Bh; Cd = Bd;
            Bh = h4; Bd = d4;
        }

        // ---- block-boundary adds: X = soft_add32(X_init, X_final) ----
        {
            double s = modred(sum_packed(sAh, sAd) + sum_packed(Ah, Ad));
            uint32_t h = (uint32_t)s;
            uint32_t dd = h & (sAh & Ah) & (sAd | Ad);
            Ah = h; Ad = dd;
        }
        {
            double s = modred(sum_packed(sBh, sBd) + sum_packed(Bh, Bd));
            uint32_t h = (uint32_t)s;
            uint32_t dd = h & (sBh & Bh) & (sBd | Bd);
            Bh = h; Bd = dd;
        }
        {
            double s = modred(sum_packed(sCh, sCd) + sum_packed(Ch, Cd));
            uint32_t h = (uint32_t)s;
            uint32_t dd = h & (sCh & Ch) & (sCd | Cd);
            Ch = h; Cd = dd;
        }
        {
            double s = modred(sum_packed(sDh, sDd) + sum_packed(Dh, Dd));
            uint32_t h = (uint32_t)s;
            uint32_t dd = h & (sDh & Dh) & (sDd | Dd);
            Dh = h; Dd = dd;
        }
    }

    // ---- emit 128 floats: hard bits, LSB-first per state word ----
    // (reference values may be w=1-2^-24 where dirty; |1 - w| = 6e-8 << 0.02)
    float4* orow = reinterpret_cast<float4*>(out) + (size_t)e * 32;
    const uint32_t H[4] = {Ah, Bh, Ch, Dh};
    #pragma unroll
    for (int hh = 0; hh < 4; ++hh) {
        #pragma unroll
        for (int q = 0; q < 8; ++q) {
            float4 v;
            v.x = (float)((H[hh] >> (q * 4 + 0)) & 1u);
            v.y = (float)((H[hh] >> (q * 4 + 1)) & 1u);
            v.z = (float)((H[hh] >> (q * 4 + 2)) & 1u);
            v.w = (float)((H[hh] >> (q * 4 + 3)) & 1u);
            orow[hh * 8 + q] = v;
        }
    }
}

extern "C" void kernel_launch(void* const* d_in, const int* in_sizes, int n_in,
                              void* d_out, int out_size, void* d_ws, size_t ws_size,
                              hipStream_t stream) {
    (void)n_in; (void)d_ws; (void)ws_size; (void)out_size;
    const float* msg = (const float*)d_in[0];
    float* out = (float*)d_out;
    const int B = in_sizes[0] / 512;
    const int block = 256;
    const int grid = (B + block - 1) / block;
    softmd5_kernel<<<grid, block, 0, stream>>>(msg, out, B);
}

// Round 3
// 673.551 us; speedup vs baseline: 1.6661x; 1.6661x over previous
//
#include <hip/hip_runtime.h>
#include <stdint.h>
#include <stddef.h>

// Bit-exact emulation of the reference's f32/f64 rounding. Contraction would
// change rounding of the literal f32 chains -> force it off globally.
#pragma clang fp contract(off)

typedef unsigned int u32;

// ===========================================================================
// Value lattice (validated bit-exact in round 2): every packed state bit is
// in {Z=0, O=1, W=1-2^-24}. The round-function output f0 (before soft_add32)
// lies in the 8-class set:
//   Z=0, O=1, W=1-2^-24, W2=1-2^-23, W4=1-2^-22, T=2^-24, U=2^-23,
//   E=2^-24-2^-48
// encoded per bit as planes: Mh (hard part h), 3-bit code c=q+4 (value =
// h + (c-4)*2^-24 - r*2^-48), Re (r plane, only class E).
// Codes: W4=0, W2=2, W=3, Z/O=4, T/E=5, U=6.
//
// Dirty table dflag(x=f0, y=state a) (exact RN32 enumeration, ties-even):
//   O:  dirty iff y=W          W,W2: dirty iff y in {O,W}
//   U:  dirty iff y=Z          Z,T,E,W4: never dirty
// => df1 = (mO & Ad) | ((mW|mW2) & Ah) | (mU & ~Ah)
// ===========================================================================

__device__ __forceinline__ u32 rotl32(u32 x, u32 n) {
    return (x << n) | (x >> (32u - n));
}

#define WF   0x1.fffffep-1f   /* w  = 1-2^-24 */
#define TWOW 0x1.fffffep+0f   /* 2w = 2-2^-23 */

// dirty flags for soft_add32(x, y) with raw float y, x in {0,1,w}:
// literal replication of proxy p = 0.5*((x+y) - (2x)*y); dirty <=> (1+p)-p != 1
__device__ __forceinline__ u32 dirty0(float y) {
#pragma clang fp contract(off)
    float p = 0.5f * y;
    float t = 1.0f + p;
    return (u32)((t - p) != 1.0f);
}
__device__ __forceinline__ u32 dirty1(float y) {
#pragma clang fp contract(off)
    float u = 1.0f + y;
    float v = y + y;          // == RN(2*y), exact
    float xr = u - v;
    float p = 0.5f * xr;
    float t = 1.0f + p;
    return (u32)((t - p) != 1.0f);
}
__device__ __forceinline__ u32 dirtyw(float y) {
#pragma clang fp contract(off)
    float u = WF + y;
    float v = TWOW * y;
    float xr = u - v;
    float p = 0.5f * xr;
    float t = 1.0f + p;
    return (u32)((t - p) != 1.0f);
}

// Sequential f64 bit-sum of a packed {0,1,w} word. Partial sums through k=28
// are exactly representable (<=53-bit span); steps 29..31 each emulated with
// one hardware RN (fma of exact products).
__device__ __forceinline__ double sum_packed(u32 h, u32 d) {
#pragma clang fp contract(off)
    double s = fma((double)(d & 0x1FFFFFFFu), -0x1p-24,
                   (double)(h & 0x1FFFFFFFu));
    int n29 = (int)(((h >> 29) & 1u) << 24) - (int)((d >> 29) & 1u);
    s = fma((double)n29, 0x1p5, s);
    int n30 = (int)(((h >> 30) & 1u) << 24) - (int)((d >> 30) & 1u);
    s = fma((double)n30, 0x1p6, s);
    int n31 = (int)((h >> 31) << 24) - (int)(d >> 31);
    s = fma((double)n31, 0x1p7, s);
    return s;
}

struct Planes { u32 Mh, QA, QB, QC, Re, mO, mWW2, mU; };

// Bit-sliced f0 classification for all 32 bits at once.
__device__ __forceinline__ Planes classes(int type, u32 Bh, u32 Bd,
                                          u32 Ch, u32 Cd, u32 Dh, u32 Dd) {
    Planes P;
    if (type <= 1) {
        // type0: F(sel=b; main=c, sub=d); type1: F(sel=d; main=b, sub=c)
        u32 selh, seld, mainh, maind, subh, subd;
        if (type == 0) { selh=Bh; seld=Bd; mainh=Ch; maind=Cd; subh=Dh; subd=Dd; }
        else           { selh=Dh; seld=Dd; mainh=Bh; maind=Bd; subh=Ch; subd=Cd; }
        u32 selZ = ~selh, selO = selh & ~seld;
        u32 mainO = mainh & ~maind, subO = subh & ~subd;
        u32 mO  = (selZ & subO) | (selO & mainO);
        u32 mW  = (selZ & subd) | (selO & maind) | (seld & mainO);
        u32 mW2 = seld & maind;
        u32 tse = seld & ~mainh;     // sel=W, main=Z: {Z,T,E} by sub
        u32 mTE = tse & subh;
        u32 mE  = tse & subd;
        P.mO = mO; P.mU = 0u;
        P.mWW2 = mW | mW2;
        P.Mh = mO | P.mWW2;
        P.QA = mW | mTE;
        P.QB = P.mWW2;
        P.QC = ~P.mWW2;
        P.Re = mE;
    } else if (type == 2) {
        // xor(xor(b,c), d)
        u32 BZ=~Bh, CZ=~Ch, DZ=~Dh;
        u32 BO=Bh&~Bd, CO=Ch&~Cd, DO=Dh&~Dd;
        u32 x1Z = (BZ&CZ)|(BO&CO);
        u32 x1O = (BZ&CO)|(BO&CZ);
        u32 x1W = (BZ&Cd)|(Bd&CZ);
        u32 x1U = (Bh&Cd)|(Bd&Ch);
        u32 mO  = (x1Z&DO)|(x1O&DZ);
        u32 mW  = (x1Z&Dd)|(x1W&DZ);
        u32 mU  = (x1O&Dd)|(x1W&Dh)|(x1U&DZ);
        u32 mW2 = x1U&DO;
        u32 mW4 = x1U&Dd;
        P.mO = mO; P.mU = mU;
        P.mWW2 = mW | mW2;
        P.Mh = mO | mW | mW2 | mW4;
        P.QA = mW;
        P.QB = mW2 | mW | mU;
        P.QC = ~(mW | mW2 | mW4);
        P.Re = 0u;
    } else {
        // xor(c, or(b, not d)); o = or(b, nd), nd: d=Z->O, d=O->Z, d=W->T
        u32 BZ=~Bh, CZ=~Ch, DZ=~Dh;
        u32 BO=Bh&~Bd, CO=Ch&~Cd, DO=Dh&~Dd;
        u32 oZ = BZ & DO;
        u32 oO = (BZ&DZ) | (BO&~Dd) | (Bd&DZ);
        u32 oW = (BO&Dd) | (Bd&Dh);
        u32 oT = BZ & Dd;
        u32 mO  = (CZ&oO)|(CO&oZ);
        u32 mW  = (CZ&oW)|(Cd&oZ);
        u32 mT  = CZ&oT;
        u32 mU  = (CO&oW)|(Cd&(oO|oW));
        u32 mW2 = Ch&oT;
        P.mO = mO; P.mU = mU;
        P.mWW2 = mW | mW2;
        P.Mh = mO | mW | mW2;
        P.QA = mW | mT;
        P.QB = mW2 | mW | mU;
        P.QC = ~(mW | mW2);
        P.Re = 0u;
    }
    return P;
}

// Sequential f64 sum of f0_k * 2^k with values assembled from planes.
// v = n*2^-24 + cd is EXACT (<=49-bit span); fma(v, 2^k, acc) is the single
// hardware RN matching the reference's sequential reduce.
__device__ __forceinline__ double chain(const Planes& P) {
#pragma clang fp contract(off)
    constexpr double CD0 = -0x1p-22;
    constexpr double CD1 = -0x1p-22 - 0x1p-48;
    double accF = 0.0;
    #pragma unroll
    for (int k = 0; k < 32; ++k) {
        u32 hb = (P.Mh >> k) & 1u;
        u32 n = (hb << 24) + ((P.QA >> k) & 1u) + (((P.QB >> k) & 1u) << 1)
              + (((P.QC >> k) & 1u) << 2);
        double cd = ((P.Re >> k) & 1u) ? CD1 : CD0;
        double v = fma((double)n, 0x1p-24, cd);
        accF = fma(v, (double)(1u << k), accF);
    }
    return accF;
}

__device__ const u32 Ku[64] = {
    0xd76aa478u,0xe8c7b756u,0x242070dbu,0xc1bdceeeu,
    0xf57c0fafu,0x4787c62au,0xa8304613u,0xfd469501u,
    0x698098d8u,0x8b44f7afu,0xffff5bb1u,0x895cd7beu,
    0x6b901122u,0xfd987193u,0xa679438eu,0x49b40821u,
    0xf61e2562u,0xc040b340u,0x265e5a51u,0xe9b6c7aau,
    0xd62f105du,0x02441453u,0xd8a1e681u,0xe7d3fbc8u,
    0x21e1cde6u,0xc33707d6u,0xf4d50d87u,0x455a14edu,
    0xa9e3e905u,0xfcefa3f8u,0x676f02d9u,0x8d2a4c8au,
    0xfffa3942u,0x8771f681u,0x6d9d6122u,0xfde5380cu,
    0xa4beea44u,0x4bdecfa9u,0xf6bb4b60u,0xbebfbc70u,
    0x289b7ec6u,0xeaa127fau,0xd4ef3085u,0x04881d05u,
    0xd9d4d039u,0xe6db99e5u,0x1fa27cf8u,0xc4ac5665u,
    0xf4292244u,0x432aff97u,0xab9423a7u,0xfc93a039u,
    0x655b59c3u,0x8f0ccc92u,0xffeff47du,0x85845dd1u,
    0x6fa87e4fu,0xfe2ce6e0u,0xa3014314u,0x4e0811a1u,
    0xf7537e82u,0xbd3af235u,0x2ad7d2bbu,0xeb86d391u
};
__device__ const u32 Stab[64] = {
    7,12,17,22, 7,12,17,22, 7,12,17,22, 7,12,17,22,
    5, 9,14,20, 5, 9,14,20, 5, 9,14,20, 5, 9,14,20,
    4,11,16,23, 4,11,16,23, 4,11,16,23, 4,11,16,23,
    6,10,15,21, 6,10,15,21, 6,10,15,21, 6,10,15,21
};
__device__ const u32 PWt[16] = { 128u,0,0,0, 0,0,0,0, 0,0,0,0, 0,0,512u,0 };

__global__ __launch_bounds__(128, 2) void softmd5_kernel(
    const float* __restrict__ msg, float* __restrict__ out, int B)
{
#pragma clang fp contract(off)
    __shared__ double lds_wv[16][128];   // 16 KB
    __shared__ u32 lds_d0[16][128];      // 8 KB  dirty(x=0, y)
    __shared__ u32 lds_d1[16][128];      // 8 KB  dirty(x=1, y)
    __shared__ u32 lds_dw[16][128];      // 8 KB  dirty(x=w, y)  => 40 KB total

    const int tid = threadIdx.x;
    const int e = blockIdx.x * 128 + tid;
    if (e >= B) return;

    const float* row = msg + (size_t)e * 512;
    const float4* r4 = reinterpret_cast<const float4*>(row);

    // ---- precompute per word: f64 value (sequential k=0..31) + 3 dirty masks
    for (int w = 0; w < 16; ++w) {
        double acc = 0.0;
        u32 m0 = 0, m1 = 0, mw = 0;
        #pragma unroll
        for (int q = 0; q < 8; ++q) {
            float4 v = r4[w * 8 + q];
            const int k = 4 * q;
            acc = fma((double)v.x, (double)(1u << (k + 0)), acc);
            acc = fma((double)v.y, (double)(1u << (k + 1)), acc);
            acc = fma((double)v.z, (double)(1u << (k + 2)), acc);
            acc = fma((double)v.w, (double)(1u << (k + 3)), acc);
            m0 |= dirty0(v.x) << (k+0); m0 |= dirty0(v.y) << (k+1);
            m0 |= dirty0(v.z) << (k+2); m0 |= dirty0(v.w) << (k+3);
            m1 |= dirty1(v.x) << (k+0); m1 |= dirty1(v.y) << (k+1);
            m1 |= dirty1(v.z) << (k+2); m1 |= dirty1(v.w) << (k+3);
            mw |= dirtyw(v.x) << (k+0); mw |= dirtyw(v.y) << (k+1);
            mw |= dirtyw(v.z) << (k+2); mw |= dirtyw(v.w) << (k+3);
        }
        lds_wv[w][tid] = acc;
        lds_d0[w][tid] = m0;
        lds_d1[w][tid] = m1;
        lds_dw[w][tid] = mw;
    }

    u32 Ah = 0x67452301u, Ad = 0u;
    u32 Bh = 0xefcdab89u, Bd = 0u;
    u32 Ch = 0x98badcfeu, Cd = 0u;
    u32 Dh = 0x10325476u, Dd = 0u;
    double vA = (double)Ah, vB = (double)Bh, vC = (double)Ch, vD = (double)Dh;

    for (int blk = 0; blk < 2; ++blk) {
        const u32 sAh=Ah, sAd=Ad, sBh=Bh, sBd=Bd;
        const u32 sCh=Ch, sCd=Cd, sDh=Dh, sDd=Dd;
        const double sVA=vA, sVB=vB, sVC=vC, sVD=vD;

        for (int i = 0; i < 64; ++i) {
            const int type = i >> 4;
            Planes P = classes(type, Bh, Bd, Ch, Cd, Dh, Dd);
            u32 df1 = (P.mO & Ad) | (P.mWW2 & Ah) | (P.mU & ~Ah);

            // add #1: f = soft_add32(f0, a)
            double accF = chain(P);
            double s1 = accF + vA;
            if (s1 >= 0x1p32) s1 -= 0x1p32;
            u32 h1 = (u32)s1, d1 = h1 & df1;
            double V1 = sum_packed(h1, d1);

            // add #2: f = soft_add32(f, K[i])   (K hard)
            double s2 = V1 + (double)Ku[i];
            if (s2 >= 0x1p32) s2 -= 0x1p32;
            u32 h2 = (u32)s2, d2 = h2 & d1 & Ku[i];
            double V2 = sum_packed(h2, d2);

            // add #3: f = soft_add32(f, words[g])
            int g;
            if (type == 0)      g = i;
            else if (type == 1) g = (5 * i + 1) & 15;
            else if (type == 2) g = (3 * i + 5) & 15;
            else                g = (7 * i) & 15;
            u32 df3; double bv;
            if (blk == 0) {
                df3 = (~h2 & lds_d0[g][tid]) | ((h2 & ~d2) & lds_d1[g][tid])
                    | (d2 & lds_dw[g][tid]);
                bv = lds_wv[g][tid];
            } else {
                u32 pw = PWt[g];
                df3 = d2 & pw;
                bv = (double)pw;
            }
            double s3 = V2 + bv;
            if (s3 >= 0x1p32) s3 -= 0x1p32;
            u32 h3 = (u32)s3, d3 = h3 & df3;

            // rotate + add #4: b = soft_add32(b, rotl(f))
            u32 sh = Stab[i];
            u32 rh = rotl32(h3, sh), rd = rotl32(d3, sh);
            double Vr = sum_packed(rh, rd);
            double s4 = vB + Vr;
            if (s4 >= 0x1p32) s4 -= 0x1p32;
            u32 h4 = (u32)s4;
            u32 d4 = h4 & (Bh & rh) & (Bd | rd);
            double V4 = sum_packed(h4, d4);

            Ah = Dh; Ad = Dd; vA = vD;
            Dh = Ch; Dd = Cd; vD = vC;
            Ch = Bh; Cd = Bd; vC = vB;
            Bh = h4; Bd = d4; vB = V4;
        }

        // block-boundary: X = soft_add32(X_init, X_final)
        {
            double s = sVA + vA; if (s >= 0x1p32) s -= 0x1p32;
            u32 h = (u32)s; u32 dd = h & (sAh & Ah) & (sAd | Ad);
            Ah = h; Ad = dd; vA = sum_packed(Ah, Ad);
        }
        {
            double s = sVB + vB; if (s >= 0x1p32) s -= 0x1p32;
            u32 h = (u32)s; u32 dd = h & (sBh & Bh) & (sBd | Bd);
            Bh = h; Bd = dd; vB = sum_packed(Bh, Bd);
        }
        {
            double s = sVC + vC; if (s >= 0x1p32) s -= 0x1p32;
            u32 h = (u32)s; u32 dd = h & (sCh & Ch) & (sCd | Cd);
            Ch = h; Cd = dd; vC = sum_packed(Ch, Cd);
        }
        {
            double s = sVD + vD; if (s >= 0x1p32) s -= 0x1p32;
            u32 h = (u32)s; u32 dd = h & (sDh & Dh) & (sDd | Dd);
            Dh = h; Dd = dd; vD = sum_packed(Dh, Dd);
        }
    }

    // ---- emit 128 floats: hard bits (|w-1|=6e-8 << 0.02 threshold)
    float4* orow = reinterpret_cast<float4*>(out) + (size_t)e * 32;
    const u32 H[4] = {Ah, Bh, Ch, Dh};
    #pragma unroll
    for (int hh = 0; hh < 4; ++hh) {
        #pragma unroll
        for (int q = 0; q < 8; ++q) {
            float4 v;
            v.x = (float)((H[hh] >> (q * 4 + 0)) & 1u);
            v.y = (float)((H[hh] >> (q * 4 + 1)) & 1u);
            v.z = (float)((H[hh] >> (q * 4 + 2)) & 1u);
            v.w = (float)((H[hh] >> (q * 4 + 3)) & 1u);
            orow[hh * 8 + q] = v;
        }
    }
}

extern "C" void kernel_launch(void* const* d_in, const int* in_sizes, int n_in,
                              void* d_out, int out_size, void* d_ws, size_t ws_size,
                              hipStream_t stream) {
    (void)n_in; (void)d_ws; (void)ws_size; (void)out_size;
    const float* msg = (const float*)d_in[0];
    float* out = (float*)d_out;
    const int B = in_sizes[0] / 512;
    const int block = 128;
    const int grid = (B + block - 1) / block;
    softmd5_kernel<<<grid, block, 0, stream>>>(msg, out, B);
}

// Round 4
// 501.440 us; speedup vs baseline: 2.2380x; 1.3432x over previous
//
#include <hip/hip_runtime.h>
#include <stdint.h>
#include <stddef.h>

// Bit-exact emulation of the reference's f32/f64 rounding. Contraction would
// change rounding of the literal f32 chains -> force it off globally.
#pragma clang fp contract(off)

typedef unsigned int u32;
typedef unsigned long long u64;

// ===========================================================================
// Value lattice (validated bit-exact, rounds 2-3): state bits in {Z,O,W},
// f0 classes {Z,O,W,W2,W4,T,U,E}; planes Mh (hard), QA/QB/QC (delta code,
// v = h + (QA+2QB+4QC-4)*2^-24 - Re*2^-48), Re (only class E).
//
// Chain-rounding theorem (this round's optimization): in the sequential f64
// reduce of f0_k*2^k, partial sums through k=28 are multiples of 2^-24 with
// magnitude < 2^29 => exactly representable => NO rounding through k=28
// UNLESS an E bit (2^-48 granularity) exists at k<=28. So for
// (Re & 0x1FFFFFFF)==0 the chain equals the exact integer sum (computed in
// int64) followed by 3 honest fma steps for k=29..31. Types 2/3 have no E
// class structurally; types 0/1 take a wave-uniform ballot.
// ===========================================================================

__device__ __forceinline__ u32 rotl32(u32 x, u32 n) {
    return (x << n) | (x >> (32u - n));
}

#define WF   0x1.fffffep-1f   /* w  = 1-2^-24 */
#define TWOW 0x1.fffffep+0f   /* 2w = 2-2^-23 */

// dirty flags for soft_add32(x, y) with raw float y, x in {0,1,w}:
// literal replication of proxy p = 0.5*((x+y) - (2x)*y); dirty <=> (1+p)-p != 1
__device__ __forceinline__ u32 dirty0(float y) {
#pragma clang fp contract(off)
    float p = 0.5f * y;
    float t = 1.0f + p;
    return (u32)((t - p) != 1.0f);
}
__device__ __forceinline__ u32 dirty1(float y) {
#pragma clang fp contract(off)
    float u = 1.0f + y;
    float v = y + y;          // == RN(2*y), exact
    float xr = u - v;
    float p = 0.5f * xr;
    float t = 1.0f + p;
    return (u32)((t - p) != 1.0f);
}
__device__ __forceinline__ u32 dirtyw(float y) {
#pragma clang fp contract(off)
    float u = WF + y;
    float v = TWOW * y;
    float xr = u - v;
    float p = 0.5f * xr;
    float t = 1.0f + p;
    return (u32)((t - p) != 1.0f);
}

// Sequential f64 bit-sum of a packed {0,1,w} word. Partial sums through k=28
// are exactly representable; steps 29..31 each emulated with one hardware RN.
__device__ __forceinline__ double sum_packed(u32 h, u32 d) {
#pragma clang fp contract(off)
    double s = fma((double)(d & 0x1FFFFFFFu), -0x1p-24,
                   (double)(h & 0x1FFFFFFFu));
    int n29 = (int)(((h >> 29) & 1u) << 24) - (int)((d >> 29) & 1u);
    s = fma((double)n29, 0x1p5, s);
    int n30 = (int)(((h >> 30) & 1u) << 24) - (int)((d >> 30) & 1u);
    s = fma((double)n30, 0x1p6, s);
    int n31 = (int)((h >> 31) << 24) - (int)(d >> 31);
    s = fma((double)n31, 0x1p7, s);
    return s;
}

struct Planes { u32 Mh, QA, QB, QC, Re, mO, mWW2, mU; };

// Bit-sliced f0 classification for all 32 bits at once (validated round 2/3).
__device__ __forceinline__ Planes classes(int type, u32 Bh, u32 Bd,
                                          u32 Ch, u32 Cd, u32 Dh, u32 Dd) {
    Planes P;
    if (type <= 1) {
        u32 selh, seld, mainh, maind, subh, subd;
        if (type == 0) { selh=Bh; seld=Bd; mainh=Ch; maind=Cd; subh=Dh; subd=Dd; }
        else           { selh=Dh; seld=Dd; mainh=Bh; maind=Bd; subh=Ch; subd=Cd; }
        u32 selZ = ~selh, selO = selh & ~seld;
        u32 mainO = mainh & ~maind, subO = subh & ~subd;
        u32 mO  = (selZ & subO) | (selO & mainO);
        u32 mW  = (selZ & subd) | (selO & maind) | (seld & mainO);
        u32 mW2 = seld & maind;
        u32 tse = seld & ~mainh;     // sel=W, main=Z: {Z,T,E} by sub
        u32 mTE = tse & subh;
        u32 mE  = tse & subd;
        P.mO = mO; P.mU = 0u;
        P.mWW2 = mW | mW2;
        P.Mh = mO | P.mWW2;
        P.QA = mW | mTE;
        P.QB = P.mWW2;
        P.QC = ~P.mWW2;
        P.Re = mE;
    } else if (type == 2) {
        u32 BZ=~Bh, CZ=~Ch, DZ=~Dh;
        u32 BO=Bh&~Bd, CO=Ch&~Cd, DO=Dh&~Dd;
        u32 x1Z = (BZ&CZ)|(BO&CO);
        u32 x1O = (BZ&CO)|(BO&CZ);
        u32 x1W = (BZ&Cd)|(Bd&CZ);
        u32 x1U = (Bh&Cd)|(Bd&Ch);
        u32 mO  = (x1Z&DO)|(x1O&DZ);
        u32 mW  = (x1Z&Dd)|(x1W&DZ);
        u32 mU  = (x1O&Dd)|(x1W&Dh)|(x1U&DZ);
        u32 mW2 = x1U&DO;
        u32 mW4 = x1U&Dd;
        P.mO = mO; P.mU = mU;
        P.mWW2 = mW | mW2;
        P.Mh = mO | mW | mW2 | mW4;
        P.QA = mW;
        P.QB = mW2 | mW | mU;
        P.QC = ~(mW | mW2 | mW4);
        P.Re = 0u;
    } else {
        u32 BZ=~Bh, CZ=~Ch, DZ=~Dh;
        u32 BO=Bh&~Bd, CO=Ch&~Cd, DO=Dh&~Dd;
        u32 oZ = BZ & DO;
        u32 oO = (BZ&DZ) | (BO&~Dd) | (Bd&DZ);
        u32 oW = (BO&Dd) | (Bd&Dh);
        u32 oT = BZ & Dd;
        u32 mO  = (CZ&oO)|(CO&oZ);
        u32 mW  = (CZ&oW)|(Cd&oZ);
        u32 mT  = CZ&oT;
        u32 mU  = (CO&oW)|(Cd&(oO|oW));
        u32 mW2 = Ch&oT;
        P.mO = mO; P.mU = mU;
        P.mWW2 = mW | mW2;
        P.Mh = mO | mW | mW2;
        P.QA = mW | mT;
        P.QB = mW2 | mW | mU;
        P.QC = ~(mW | mW2);
        P.Re = 0u;
    }
    return P;
}

// per-bit f0 value: v = n*2^-24 + cd (exact assembly, <=49-bit span)
__device__ __forceinline__ double vbit(const Planes& P, int k) {
#pragma clang fp contract(off)
    u32 hb = (P.Mh >> k) & 1u;
    u32 n = (hb << 24) + ((P.QA >> k) & 1u) + (((P.QB >> k) & 1u) << 1)
          + (((P.QC >> k) & 1u) << 2);
    double cd = ((P.Re >> k) & 1u) ? (-0x1p-22 - 0x1p-48) : -0x1p-22;
    return fma((double)n, 0x1p-24, cd);
}

// Honest sequential chain (exactly replicates all mid-chain roundings).
__device__ __forceinline__ double chain_slow(const Planes& P) {
#pragma clang fp contract(off)
    double accF = 0.0;
    #pragma unroll
    for (int k = 0; k < 32; ++k)
        accF = fma(vbit(P, k), (double)(1u << k), accF);
    return accF;
}

// Fast chain, valid iff (Re & 0x1FFFFFFF)==0: steps k<=28 are provably
// rounding-free => exact integer sum; then 3 honest fma steps.
// I = sum_{k<=28} ((h<<24) + QA+2QB+4QC-4) * 2^k; per-bit term >= 0,
// I <= 2^24*(2^29-1) < 2^53 => hi/lo f64 assembly is exact.
__device__ __forceinline__ double chain_fast(const Planes& P) {
#pragma clang fp contract(off)
    const u32 M29 = 0x1FFFFFFFu;
    u32 lo = (P.QA & M29) + ((P.QB & M29) << 1) + ((P.QC & M29) << 2);
    u64 I = (((u64)(P.Mh & M29)) << 24) + (u64)lo - 0x7FFFFFFCull; // -4*(2^29-1)
    double X = fma((double)(u32)(I >> 32), 0x1p32, (double)(u32)I); // exact
    double accF = X * 0x1p-24;                                     // exact
    accF = fma(vbit(P, 29), 0x1p29, accF);
    accF = fma(vbit(P, 30), 0x1p30, accF);
    accF = fma(vbit(P, 31), 0x1p31, accF);
    return accF;
}

__device__ const u32 Ku[64] = {
    0xd76aa478u,0xe8c7b756u,0x242070dbu,0xc1bdceeeu,
    0xf57c0fafu,0x4787c62au,0xa8304613u,0xfd469501u,
    0x698098d8u,0x8b44f7afu,0xffff5bb1u,0x895cd7beu,
    0x6b901122u,0xfd987193u,0xa679438eu,0x49b40821u,
    0xf61e2562u,0xc040b340u,0x265e5a51u,0xe9b6c7aau,
    0xd62f105du,0x02441453u,0xd8a1e681u,0xe7d3fbc8u,
    0x21e1cde6u,0xc33707d6u,0xf4d50d87u,0x455a14edu,
    0xa9e3e905u,0xfcefa3f8u,0x676f02d9u,0x8d2a4c8au,
    0xfffa3942u,0x8771f681u,0x6d9d6122u,0xfde5380cu,
    0xa4beea44u,0x4bdecfa9u,0xf6bb4b60u,0xbebfbc70u,
    0x289b7ec6u,0xeaa127fau,0xd4ef3085u,0x04881d05u,
    0xd9d4d039u,0xe6db99e5u,0x1fa27cf8u,0xc4ac5665u,
    0xf4292244u,0x432aff97u,0xab9423a7u,0xfc93a039u,
    0x655b59c3u,0x8f0ccc92u,0xffeff47du,0x85845dd1u,
    0x6fa87e4fu,0xfe2ce6e0u,0xa3014314u,0x4e0811a1u,
    0xf7537e82u,0xbd3af235u,0x2ad7d2bbu,0xeb86d391u
};
__device__ const u32 Stab[64] = {
    7,12,17,22, 7,12,17,22, 7,12,17,22, 7,12,17,22,
    5, 9,14,20, 5, 9,14,20, 5, 9,14,20, 5, 9,14,20,
    4,11,16,23, 4,11,16,23, 4,11,16,23, 4,11,16,23,
    6,10,15,21, 6,10,15,21, 6,10,15,21, 6,10,15,21
};
__device__ const u32 PWt[16] = { 128u,0,0,0, 0,0,0,0, 0,0,0,0, 0,0,512u,0 };

// One MD5 soft-round. TYPE is a compile-time constant; blk folded by unroll.
#define ROUND(TYPE, i, g)                                                     \
    {                                                                         \
        Planes P = classes(TYPE, Bh, Bd, Ch, Cd, Dh, Dd);                     \
        u32 df1 = (P.mO & Ad) | (P.mWW2 & Ah) | (P.mU & ~Ah);                 \
        double accF;                                                          \
        if (TYPE >= 2) {                                                      \
            accF = chain_fast(P);                                             \
        } else if (__ballot((P.Re & 0x1FFFFFFFu) != 0u) == 0ull) {            \
            accF = chain_fast(P);                                             \
        } else {                                                              \
            accF = chain_slow(P);                                             \
        }                                                                     \
        double s1 = accF + vA; if (s1 >= 0x1p32) s1 -= 0x1p32;                \
        u32 h1 = (u32)s1, d1 = h1 & df1;                                      \
        double V1 = sum_packed(h1, d1);                                       \
        u32 Kv = Ku[i];                                                       \
        double s2 = V1 + (double)Kv; if (s2 >= 0x1p32) s2 -= 0x1p32;          \
        u32 h2 = (u32)s2, d2 = h2 & d1 & Kv;                                  \
        double V2 = sum_packed(h2, d2);                                       \
        u32 df3; double bv;                                                   \
        if (blk == 0) {                                                       \
            df3 = (~h2 & lds_d0[g][tid]) | ((h2 & ~d2) & lds_d1[g][tid])      \
                | (d2 & lds_dw[g][tid]);                                      \
            bv = lds_wv[g][tid];                                              \
        } else {                                                              \
            u32 pw = PWt[g];                                                  \
            df3 = d2 & pw;                                                    \
            bv = (double)pw;                                                  \
        }                                                                     \
        double s3 = V2 + bv; if (s3 >= 0x1p32) s3 -= 0x1p32;                  \
        u32 h3 = (u32)s3, d3 = h3 & df3;                                      \
        u32 sh = Stab[i];                                                     \
        u32 rh = rotl32(h3, sh), rd = rotl32(d3, sh);                         \
        double Vr = sum_packed(rh, rd);                                       \
        double s4 = vB + Vr; if (s4 >= 0x1p32) s4 -= 0x1p32;                  \
        u32 h4 = (u32)s4;                                                     \
        u32 d4 = h4 & (Bh & rh) & (Bd | rd);                                  \
        double V4 = sum_packed(h4, d4);                                       \
        Ah = Dh; Ad = Dd; vA = vD;                                            \
        Dh = Ch; Dd = Cd; vD = vC;                                            \
        Ch = Bh; Cd = Bd; vC = vB;                                            \
        Bh = h4; Bd = d4; vB = V4;                                            \
    }

__global__ __launch_bounds__(128, 2) void softmd5_kernel(
    const float* __restrict__ msg, float* __restrict__ out, int B)
{
#pragma clang fp contract(off)
    __shared__ double lds_wv[16][128];   // 16 KB
    __shared__ u32 lds_d0[16][128];      // 8 KB  dirty(x=0, y)
    __shared__ u32 lds_d1[16][128];      // 8 KB  dirty(x=1, y)
    __shared__ u32 lds_dw[16][128];      // 8 KB  dirty(x=w, y)  => 40 KB total

    const int tid = threadIdx.x;
    const int e = blockIdx.x * 128 + tid;
    if (e >= B) return;

    const float* row = msg + (size_t)e * 512;
    const float4* r4 = reinterpret_cast<const float4*>(row);

    // ---- precompute per word: f64 value (sequential k=0..31) + 3 dirty masks
    for (int w = 0; w < 16; ++w) {
        double acc = 0.0;
        u32 m0 = 0, m1 = 0, mw = 0;
        #pragma unroll
        for (int q = 0; q < 8; ++q) {
            float4 v = r4[w * 8 + q];
            const int k = 4 * q;
            acc = fma((double)v.x, (double)(1u << (k + 0)), acc);
            acc = fma((double)v.y, (double)(1u << (k + 1)), acc);
            acc = fma((double)v.z, (double)(1u << (k + 2)), acc);
            acc = fma((double)v.w, (double)(1u << (k + 3)), acc);
            m0 |= dirty0(v.x) << (k+0); m0 |= dirty0(v.y) << (k+1);
            m0 |= dirty0(v.z) << (k+2); m0 |= dirty0(v.w) << (k+3);
            m1 |= dirty1(v.x) << (k+0); m1 |= dirty1(v.y) << (k+1);
            m1 |= dirty1(v.z) << (k+2); m1 |= dirty1(v.w) << (k+3);
            mw |= dirtyw(v.x) << (k+0); mw |= dirtyw(v.y) << (k+1);
            mw |= dirtyw(v.z) << (k+2); mw |= dirtyw(v.w) << (k+3);
        }
        lds_wv[w][tid] = acc;
        lds_d0[w][tid] = m0;
        lds_d1[w][tid] = m1;
        lds_dw[w][tid] = mw;
    }

    u32 Ah = 0x67452301u, Ad = 0u;
    u32 Bh = 0xefcdab89u, Bd = 0u;
    u32 Ch = 0x98badcfeu, Cd = 0u;
    u32 Dh = 0x10325476u, Dd = 0u;
    double vA = (double)Ah, vB = (double)Bh, vC = (double)Ch, vD = (double)Dh;

    #pragma unroll
    for (int blk = 0; blk < 2; ++blk) {
        const u32 sAh=Ah, sAd=Ad, sBh=Bh, sBd=Bd;
        const u32 sCh=Ch, sCd=Cd, sDh=Dh, sDd=Dd;
        const double sVA=vA, sVB=vB, sVC=vC, sVD=vD;

        #pragma unroll 1
        for (int i = 0; i < 16; ++i) ROUND(0, i, i)
        #pragma unroll 1
        for (int i = 16; i < 32; ++i) ROUND(1, i, (5 * i + 1) & 15)
        #pragma unroll 1
        for (int i = 32; i < 48; ++i) ROUND(2, i, (3 * i + 5) & 15)
        #pragma unroll 1
        for (int i = 48; i < 64; ++i) ROUND(3, i, (7 * i) & 15)

        // block-boundary: X = soft_add32(X_init, X_final)
        {
            double s = sVA + vA; if (s >= 0x1p32) s -= 0x1p32;
            u32 h = (u32)s; u32 dd = h & (sAh & Ah) & (sAd | Ad);
            Ah = h; Ad = dd; vA = sum_packed(Ah, Ad);
        }
        {
            double s = sVB + vB; if (s >= 0x1p32) s -= 0x1p32;
            u32 h = (u32)s; u32 dd = h & (sBh & Bh) & (sBd | Bd);
            Bh = h; Bd = dd; vB = sum_packed(Bh, Bd);
        }
        {
            double s = sVC + vC; if (s >= 0x1p32) s -= 0x1p32;
            u32 h = (u32)s; u32 dd = h & (sCh & Ch) & (sCd | Cd);
            Ch = h; Cd = dd; vC = sum_packed(Ch, Cd);
        }
        {
            double s = sVD + vD; if (s >= 0x1p32) s -= 0x1p32;
            u32 h = (u32)s; u32 dd = h & (sDh & Dh) & (sDd | Dd);
            Dh = h; Dd = dd; vD = sum_packed(Dh, Dd);
        }
    }

    // ---- emit 128 floats: hard bits (|w-1|=6e-8 << 0.02 threshold)
    float4* orow = reinterpret_cast<float4*>(out) + (size_t)e * 32;
    const u32 H[4] = {Ah, Bh, Ch, Dh};
    #pragma unroll
    for (int hh = 0; hh < 4; ++hh) {
        #pragma unroll
        for (int q = 0; q < 8; ++q) {
            float4 v;
            v.x = (float)((H[hh] >> (q * 4 + 0)) & 1u);
            v.y = (float)((H[hh] >> (q * 4 + 1)) & 1u);
            v.z = (float)((H[hh] >> (q * 4 + 2)) & 1u);
            v.w = (float)((H[hh] >> (q * 4 + 3)) & 1u);
            orow[hh * 8 + q] = v;
        }
    }
}

extern "C" void kernel_launch(void* const* d_in, const int* in_sizes, int n_in,
                              void* d_out, int out_size, void* d_ws, size_t ws_size,
                              hipStream_t stream) {
    (void)n_in; (void)d_ws; (void)ws_size; (void)out_size;
    const float* msg = (const float*)d_in[0];
    float* out = (float*)d_out;
    const int B = in_sizes[0] / 512;
    const int block = 128;
    const int grid = (B + block - 1) / block;
    softmd5_kernel<<<grid, block, 0, stream>>>(msg, out, B);
}

// Round 6
// 478.809 us; speedup vs baseline: 2.3438x; 1.0473x over previous
//
#include <hip/hip_runtime.h>
#include <stdint.h>
#include <stddef.h>

// Bit-exact emulation of the reference's f32/f64 rounding. Contraction would
// change rounding of the literal f32 chains -> force it off globally.
#pragma clang fp contract(off)

typedef unsigned int u32;
typedef unsigned long long u64;

// ===========================================================================
// Validated machinery (rounds 2-4): state bits in {Z=0, O=1, W=1-2^-24},
// packed (hard,dirty) masks; f0 classes {Z,O,W,W2,W4,T,U,E} as planes
// Mh/QA/QB/QC/Re (v = h + (QA+2QB+4QC-4)*2^-24 - Re*2^-48).
//
// Round-6 fix: round 5's chain_slow computed __builtin_ctz(0) for lanes with
// no E bit that were dragged down the slow path by the wave ballot (UB ->
// v_ffbl returns -1 -> garbage). kE = (ReL==0) ? 29 : ctz(ReL); the prefix
// formula at kE=29 degenerates exactly to chain_fast.
// ===========================================================================

__device__ __forceinline__ u32 rotl32(u32 x, u32 n) {
    return (x << n) | (x >> (32u - n));
}

#define WF   0x1.fffffep-1f   /* w  = 1-2^-24 */
#define TWOW 0x1.fffffep+0f   /* 2w = 2-2^-23 */

// dirty flags for soft_add32(x, y) with raw float y, x in {0,1,w}
__device__ __forceinline__ u32 dirty0(float y) {
#pragma clang fp contract(off)
    float p = 0.5f * y;
    float t = 1.0f + p;
    return (u32)((t - p) != 1.0f);
}
__device__ __forceinline__ u32 dirty1(float y) {
#pragma clang fp contract(off)
    float u = 1.0f + y;
    float v = y + y;
    float xr = u - v;
    float p = 0.5f * xr;
    float t = 1.0f + p;
    return (u32)((t - p) != 1.0f);
}
__device__ __forceinline__ u32 dirtyw(float y) {
#pragma clang fp contract(off)
    float u = WF + y;
    float v = TWOW * y;
    float xr = u - v;
    float p = 0.5f * xr;
    float t = 1.0f + p;
    return (u32)((t - p) != 1.0f);
}

// Sequential f64 bit-sum of a packed {0,1,w} word (validated).
__device__ __forceinline__ double sum_packed(u32 h, u32 d) {
#pragma clang fp contract(off)
    double s = fma((double)(d & 0x1FFFFFFFu), -0x1p-24,
                   (double)(h & 0x1FFFFFFFu));
    int n29 = (int)(((h >> 29) & 1u) << 24) - (int)((d >> 29) & 1u);
    s = fma((double)n29, 0x1p5, s);
    int n30 = (int)(((h >> 30) & 1u) << 24) - (int)((d >> 30) & 1u);
    s = fma((double)n30, 0x1p6, s);
    int n31 = (int)((h >> 31) << 24) - (int)(d >> 31);
    s = fma((double)n31, 0x1p7, s);
    return s;
}

struct Planes { u32 Mh, QA, QB, QC, Re, mO, mWW2, mU; };

// Bit-sliced f0 classification (validated rounds 2-4).
__device__ __forceinline__ Planes classes(int type, u32 Bh, u32 Bd,
                                          u32 Ch, u32 Cd, u32 Dh, u32 Dd) {
    Planes P;
    if (type <= 1) {
        u32 selh, seld, mainh, maind, subh, subd;
        if (type == 0) { selh=Bh; seld=Bd; mainh=Ch; maind=Cd; subh=Dh; subd=Dd; }
        else           { selh=Dh; seld=Dd; mainh=Bh; maind=Bd; subh=Ch; subd=Cd; }
        u32 selZ = ~selh, selO = selh & ~seld;
        u32 mainO = mainh & ~maind, subO = subh & ~subd;
        u32 mO  = (selZ & subO) | (selO & mainO);
        u32 mW  = (selZ & subd) | (selO & maind) | (seld & mainO);
        u32 mW2 = seld & maind;
        u32 tse = seld & ~mainh;
        u32 mTE = tse & subh;
        u32 mE  = tse & subd;
        P.mO = mO; P.mU = 0u;
        P.mWW2 = mW | mW2;
        P.Mh = mO | P.mWW2;
        P.QA = mW | mTE;
        P.QB = P.mWW2;
        P.QC = ~P.mWW2;
        P.Re = mE;
    } else if (type == 2) {
        u32 BZ=~Bh, CZ=~Ch, DZ=~Dh;
        u32 BO=Bh&~Bd, CO=Ch&~Cd, DO=Dh&~Dd;
        u32 x1Z = (BZ&CZ)|(BO&CO);
        u32 x1O = (BZ&CO)|(BO&CZ);
        u32 x1W = (BZ&Cd)|(Bd&CZ);
        u32 x1U = (Bh&Cd)|(Bd&Ch);
        u32 mO  = (x1Z&DO)|(x1O&DZ);
        u32 mW  = (x1Z&Dd)|(x1W&DZ);
        u32 mU  = (x1O&Dd)|(x1W&Dh)|(x1U&DZ);
        u32 mW2 = x1U&DO;
        u32 mW4 = x1U&Dd;
        P.mO = mO; P.mU = mU;
        P.mWW2 = mW | mW2;
        P.Mh = mO | mW | mW2 | mW4;
        P.QA = mW;
        P.QB = mW2 | mW | mU;
        P.QC = ~(mW | mW2 | mW4);
        P.Re = 0u;
    } else {
        u32 BZ=~Bh, CZ=~Ch, DZ=~Dh;
        u32 BO=Bh&~Bd, CO=Ch&~Cd, DO=Dh&~Dd;
        u32 oZ = BZ & DO;
        u32 oO = (BZ&DZ) | (BO&~Dd) | (Bd&DZ);
        u32 oW = (BO&Dd) | (Bd&Dh);
        u32 oT = BZ & Dd;
        u32 mO  = (CZ&oO)|(CO&oZ);
        u32 mW  = (CZ&oW)|(Cd&oZ);
        u32 mT  = CZ&oT;
        u32 mU  = (CO&oW)|(Cd&(oO|oW));
        u32 mW2 = Ch&oT;
        P.mO = mO; P.mU = mU;
        P.mWW2 = mW | mW2;
        P.Mh = mO | mW | mW2;
        P.QA = mW | mT;
        P.QB = mW2 | mW | mU;
        P.QC = ~(mW | mW2);
        P.Re = 0u;
    }
    return P;
}

// per-bit f0 value: v = n*2^-24 + cd (exact assembly)
__device__ __forceinline__ double vbit(const Planes& P, int k) {
#pragma clang fp contract(off)
    u32 hb = (P.Mh >> k) & 1u;
    u32 n = (hb << 24) + ((P.QA >> k) & 1u) + (((P.QB >> k) & 1u) << 1)
          + (((P.QC >> k) & 1u) << 2);
    double cd = ((P.Re >> k) & 1u) ? (-0x1p-22 - 0x1p-48) : -0x1p-22;
    return fma((double)n, 0x1p-24, cd);
}

// Slow chain with exact prefix: bits below kE are rounding-free (chain_fast
// theorem on an E-free prefix) -> closed-form integer; honest sequential fma
// from kE. ROUND-6 FIX: lanes with ReL==0 (dragged here by the wave ballot)
// use kE=29, which degenerates exactly to chain_fast.
__device__ double chain_slow(const Planes& P) {
#pragma clang fp contract(off)
    u32 ReL = P.Re & 0x1FFFFFFFu;
    int kE = (ReL == 0u) ? 29 : __builtin_ctz(ReL);
    u32 pm = (1u << kE) - 1u;           // kE in [0,29]
    u32 lo = (P.QA & pm) + ((P.QB & pm) << 1) + ((P.QC & pm) << 2);
    u64 I = (((u64)(P.Mh & pm)) << 24) + (u64)lo - ((4ull << kE) - 4ull);
    double S = fma((double)(u32)(I >> 32), 0x1p32, (double)(u32)I) * 0x1p-24;
    for (int k = kE; k < 32; ++k)
        S = fma(vbit(P, k), (double)(1u << k), S);
    return S;
}

// Fast chain, valid iff (Re & 0x1FFFFFFF)==0 (validated round 4).
__device__ __forceinline__ double chain_fast(const Planes& P) {
#pragma clang fp contract(off)
    const u32 M29 = 0x1FFFFFFFu;
    u32 lo = (P.QA & M29) + ((P.QB & M29) << 1) + ((P.QC & M29) << 2);
    u64 I = (((u64)(P.Mh & M29)) << 24) + (u64)lo - 0x7FFFFFFCull;
    double X = fma((double)(u32)(I >> 32), 0x1p32, (double)(u32)I);
    double accF = X * 0x1p-24;
    accF = fma(vbit(P, 29), 0x1p29, accF);
    accF = fma(vbit(P, 30), 0x1p30, accF);
    accF = fma(vbit(P, 31), 0x1p31, accF);
    return accF;
}

__device__ const u32 Ku[64] = {
    0xd76aa478u,0xe8c7b756u,0x242070dbu,0xc1bdceeeu,
    0xf57c0fafu,0x4787c62au,0xa8304613u,0xfd469501u,
    0x698098d8u,0x8b44f7afu,0xffff5bb1u,0x895cd7beu,
    0x6b901122u,0xfd987193u,0xa679438eu,0x49b40821u,
    0xf61e2562u,0xc040b340u,0x265e5a51u,0xe9b6c7aau,
    0xd62f105du,0x02441453u,0xd8a1e681u,0xe7d3fbc8u,
    0x21e1cde6u,0xc33707d6u,0xf4d50d87u,0x455a14edu,
    0xa9e3e905u,0xfcefa3f8u,0x676f02d9u,0x8d2a4c8au,
    0xfffa3942u,0x8771f681u,0x6d9d6122u,0xfde5380cu,
    0xa4beea44u,0x4bdecfa9u,0xf6bb4b60u,0xbebfbc70u,
    0x289b7ec6u,0xeaa127fau,0xd4ef3085u,0x04881d05u,
    0xd9d4d039u,0xe6db99e5u,0x1fa27cf8u,0xc4ac5665u,
    0xf4292244u,0x432aff97u,0xab9423a7u,0xfc93a039u,
    0x655b59c3u,0x8f0ccc92u,0xffeff47du,0x85845dd1u,
    0x6fa87e4fu,0xfe2ce6e0u,0xa3014314u,0x4e0811a1u,
    0xf7537e82u,0xbd3af235u,0x2ad7d2bbu,0xeb86d391u
};
__device__ const u32 Stab[64] = {
    7,12,17,22, 7,12,17,22, 7,12,17,22, 7,12,17,22,
    5, 9,14,20, 5, 9,14,20, 5, 9,14,20, 5, 9,14,20,
    4,11,16,23, 4,11,16,23, 4,11,16,23, 4,11,16,23,
    6,10,15,21, 6,10,15,21, 6,10,15,21, 6,10,15,21
};
__device__ const u32 PWt[16] = { 128u,0,0,0, 0,0,0,0, 0,0,0,0, 0,0,512u,0 };

// Soft round. WSEL: 0 -> LDS message word (block 0); 1 -> PW word (block 1).
#define ROUND(TYPE, WSEL, i, g)                                               \
    {                                                                         \
        Planes P = classes(TYPE, Bh, Bd, Ch, Cd, Dh, Dd);                     \
        u32 df1 = (P.mO & Ad) | (P.mWW2 & Ah) | (P.mU & ~Ah);                 \
        double accF;                                                          \
        if (TYPE >= 2) {                                                      \
            accF = chain_fast(P);                                             \
        } else if (__ballot((P.Re & 0x1FFFFFFFu) != 0u) == 0ull) {            \
            accF = chain_fast(P);                                             \
        } else {                                                              \
            accF = chain_slow(P);                                             \
        }                                                                     \
        double s1 = accF + vA; if (s1 >= 0x1p32) s1 -= 0x1p32;                \
        u32 h1 = (u32)s1, d1 = h1 & df1;                                      \
        double V1 = sum_packed(h1, d1);                                       \
        u32 Kv = Ku[i];                                                       \
        double s2 = V1 + (double)Kv; if (s2 >= 0x1p32) s2 -= 0x1p32;          \
        u32 h2 = (u32)s2, d2 = h2 & d1 & Kv;                                  \
        double V2 = sum_packed(h2, d2);                                       \
        u32 df3; double bv;                                                   \
        if (WSEL == 0) {                                                      \
            df3 = (~h2 & lds_d0[g][tid]) | ((h2 & ~d2) & lds_d1[g][tid])      \
                | (d2 & lds_dw[g][tid]);                                      \
            bv = lds_wv[g][tid];                                              \
        } else {                                                              \
            u32 pw = PWt[g];                                                  \
            df3 = d2 & pw;                                                    \
            bv = (double)pw;                                                  \
        }                                                                     \
        double s3 = V2 + bv; if (s3 >= 0x1p32) s3 -= 0x1p32;                  \
        u32 h3 = (u32)s3, d3 = h3 & df3;                                      \
        u32 sh = Stab[i];                                                     \
        u32 rh = rotl32(h3, sh), rd = rotl32(d3, sh);                         \
        double Vr = sum_packed(rh, rd);                                       \
        double s4 = vB + Vr; if (s4 >= 0x1p32) s4 -= 0x1p32;                  \
        u32 h4 = (u32)s4;                                                     \
        u32 d4 = h4 & (Bh & rh) & (Bd | rd);                                  \
        double V4 = sum_packed(h4, d4);                                       \
        Ah = Dh; Ad = Dd; vA = vD;                                            \
        Dh = Ch; Dd = Cd; vD = vC;                                            \
        Ch = Bh; Cd = Bd; vC = vB;                                            \
        Bh = h4; Bd = d4; vB = V4;                                            \
    }

// Pure-integer round: valid when all dirt masks are zero (exactly equals the
// reference's f64 semantics on hard bits — all f32/f64 ops exact).
#define INTROUND(TYPE, i, g)                                                  \
    {                                                                         \
        u32 f;                                                                \
        if (TYPE == 0)      f = (Bh & Ch) | (~Bh & Dh);                       \
        else if (TYPE == 1) f = (Dh & Bh) | (~Dh & Ch);                       \
        else if (TYPE == 2) f = Bh ^ Ch ^ Dh;                                 \
        else                f = Ch ^ (Bh | ~Dh);                              \
        f += Ah + Ku[i] + PWt[g];                                             \
        u32 nb = Bh + rotl32(f, Stab[i]);                                     \
        Ah = Dh; Dh = Ch; Ch = Bh; Bh = nb;                                   \
    }

// Block-1 round: sticky wave-uniform switch to int mode once dirt-free.
#define B1ROUND(TYPE, i, g)                                                   \
    {                                                                         \
        if (!intm) intm = (__ballot((Ad | Bd | Cd | Dd) != 0u) == 0ull);      \
        if (intm) INTROUND(TYPE, i, g)                                        \
        else      ROUND(TYPE, 1, i, g)                                        \
    }

__global__ __launch_bounds__(128, 2) void softmd5_kernel(
    const float* __restrict__ msg, float* __restrict__ out, int B)
{
#pragma clang fp contract(off)
    __shared__ double lds_wv[16][128];   // 16 KB
    __shared__ u32 lds_d0[16][128];      // 8 KB
    __shared__ u32 lds_d1[16][128];      // 8 KB
    __shared__ u32 lds_dw[16][128];      // 8 KB  => 40 KB total

    const int tid = threadIdx.x;
    const int e = blockIdx.x * 128 + tid;
    if (e >= B) return;

    const float* row = msg + (size_t)e * 512;
    const float4* r4 = reinterpret_cast<const float4*>(row);

    // per-word precompute: f64 value (sequential k=0..31) + 3 dirty masks
    for (int w = 0; w < 16; ++w) {
        double acc = 0.0;
        u32 m0 = 0, m1 = 0, mw = 0;
        #pragma unroll
        for (int q = 0; q < 8; ++q) {
            float4 v = r4[w * 8 + q];
            const int k = 4 * q;
            acc = fma((double)v.x, (double)(1u << (k + 0)), acc);
            acc = fma((double)v.y, (double)(1u << (k + 1)), acc);
            acc = fma((double)v.z, (double)(1u << (k + 2)), acc);
            acc = fma((double)v.w, (double)(1u << (k + 3)), acc);
            m0 |= dirty0(v.x) << (k+0); m0 |= dirty0(v.y) << (k+1);
            m0 |= dirty0(v.z) << (k+2); m0 |= dirty0(v.w) << (k+3);
            m1 |= dirty1(v.x) << (k+0); m1 |= dirty1(v.y) << (k+1);
            m1 |= dirty1(v.z) << (k+2); m1 |= dirty1(v.w) << (k+3);
            mw |= dirtyw(v.x) << (k+0); mw |= dirtyw(v.y) << (k+1);
            mw |= dirtyw(v.z) << (k+2); mw |= dirtyw(v.w) << (k+3);
        }
        lds_wv[w][tid] = acc;
        lds_d0[w][tid] = m0;
        lds_d1[w][tid] = m1;
        lds_dw[w][tid] = mw;
    }

    u32 Ah = 0x67452301u, Ad = 0u;
    u32 Bh = 0xefcdab89u, Bd = 0u;
    u32 Ch = 0x98badcfeu, Cd = 0u;
    u32 Dh = 0x10325476u, Dd = 0u;
    double vA = (double)Ah, vB = (double)Bh, vC = (double)Ch, vD = (double)Dh;

    // ================= block 0 (fractional message words) =================
    {
        const u32 sAh=Ah, sAd=Ad, sBh=Bh, sBd=Bd;
        const u32 sCh=Ch, sCd=Cd, sDh=Dh, sDd=Dd;
        const double sVA=vA, sVB=vB, sVC=vC, sVD=vD;

        #pragma unroll 1
        for (int i = 0; i < 16; ++i) ROUND(0, 0, i, i)
        #pragma unroll 1
        for (int i = 16; i < 32; ++i) ROUND(1, 0, i, (5 * i + 1) & 15)
        #pragma unroll 1
        for (int i = 32; i < 48; ++i) ROUND(2, 0, i, (3 * i + 5) & 15)
        #pragma unroll 1
        for (int i = 48; i < 64; ++i) ROUND(3, 0, i, (7 * i) & 15)

        {
            double s = sVA + vA; if (s >= 0x1p32) s -= 0x1p32;
            u32 h = (u32)s; u32 dd = h & (sAh & Ah) & (sAd | Ad);
            Ah = h; Ad = dd; vA = sum_packed(Ah, Ad);
        }
        {
            double s = sVB + vB; if (s >= 0x1p32) s -= 0x1p32;
            u32 h = (u32)s; u32 dd = h & (sBh & Bh) & (sBd | Bd);
            Bh = h; Bd = dd; vB = sum_packed(Bh, Bd);
        }
        {
            double s = sVC + vC; if (s >= 0x1p32) s -= 0x1p32;
            u32 h = (u32)s; u32 dd = h & (sCh & Ch) & (sCd | Cd);
            Ch = h; Cd = dd; vC = sum_packed(Ch, Cd);
        }
        {
            double s = sVD + vD; if (s >= 0x1p32) s -= 0x1p32;
            u32 h = (u32)s; u32 dd = h & (sDh & Dh) & (sDd | Dd);
            Dh = h; Dd = dd; vD = sum_packed(Dh, Dd);
        }
    }

    // ================= block 1 (hard pad words; dirt decays) ==============
    {
        const u32 sAh=Ah, sAd=Ad, sBh=Bh, sBd=Bd;
        const u32 sCh=Ch, sCd=Cd, sDh=Dh, sDd=Dd;
        const double sVA=vA, sVB=vB, sVC=vC, sVD=vD;
        bool intm = false;

        #pragma unroll 1
        for (int i = 0; i < 16; ++i) B1ROUND(0, i, i)
        #pragma unroll 1
        for (int i = 16; i < 32; ++i) B1ROUND(1, i, (5 * i + 1) & 15)
        #pragma unroll 1
        for (int i = 32; i < 48; ++i) B1ROUND(2, i, (3 * i + 5) & 15)
        #pragma unroll 1
        for (int i = 48; i < 64; ++i) B1ROUND(3, i, (7 * i) & 15)

        if (intm) {   // dirt-free: values are the plain integers
            vA = (double)Ah; vB = (double)Bh; vC = (double)Ch; vD = (double)Dh;
        }

        {
            double s = sVA + vA; if (s >= 0x1p32) s -= 0x1p32;
            u32 h = (u32)s; u32 dd = h & (sAh & Ah) & (sAd | Ad);
            Ah = h; Ad = dd;
        }
        {
            double s = sVB + vB; if (s >= 0x1p32) s -= 0x1p32;
            u32 h = (u32)s; u32 dd = h & (sBh & Bh) & (sBd | Bd);
            Bh = h; Bd = dd;
        }
        {
            double s = sVC + vC; if (s >= 0x1p32) s -= 0x1p32;
            u32 h = (u32)s; u32 dd = h & (sCh & Ch) & (sCd | Cd);
            Ch = h; Cd = dd;
        }
        {
            double s = sVD + vD; if (s >= 0x1p32) s -= 0x1p32;
            u32 h = (u32)s; u32 dd = h & (sDh & Dh) & (sDd | Dd);
            Dh = h; Dd = dd;
        }
    }

    // ---- emit 128 floats: hard bits (|w-1|=6e-8 << 0.02 threshold)
    float4* orow = reinterpret_cast<float4*>(out) + (size_t)e * 32;
    const u32 H[4] = {Ah, Bh, Ch, Dh};
    #pragma unroll
    for (int hh = 0; hh < 4; ++hh) {
        #pragma unroll
        for (int q = 0; q < 8; ++q) {
            float4 v;
            v.x = (float)((H[hh] >> (q * 4 + 0)) & 1u);
            v.y = (float)((H[hh] >> (q * 4 + 1)) & 1u);
            v.z = (float)((H[hh] >> (q * 4 + 2)) & 1u);
            v.w = (float)((H[hh] >> (q * 4 + 3)) & 1u);
            orow[hh * 8 + q] = v;
        }
    }
}

extern "C" void kernel_launch(void* const* d_in, const int* in_sizes, int n_in,
                              void* d_out, int out_size, void* d_ws, size_t ws_size,
                              hipStream_t stream) {
    (void)n_in; (void)d_ws; (void)ws_size; (void)out_size;
    const float* msg = (const float*)d_in[0];
    float* out = (float*)d_out;
    const int B = in_sizes[0] / 512;
    const int block = 128;
    const int grid = (B + block - 1) / block;
    softmd5_kernel<<<grid, block, 0, stream>>>(msg, out, B);
}